// Round 3
// baseline (4146.608 us; speedup 1.0000x reference)
//
#include <hip/hip_runtime.h>
#include <hip/hip_bf16.h>
#include <math.h>

typedef __bf16 bf16_t;
typedef __bf16 bf16x8 __attribute__((ext_vector_type(8)));
typedef __bf16 bf16x4 __attribute__((ext_vector_type(4)));
typedef float  f32x4  __attribute__((ext_vector_type(4)));
typedef short  s16x4  __attribute__((ext_vector_type(4)));

#define S_LEN 4096
#define DMODEL 768
#define NHEAD 12
#define NLAYER 12
#define FFDIM 3072

// ---- MFMA helpers -------------------------------------------------------
static __device__ inline f32x4 mfma16x16x16(bf16x4 a, bf16x4 b, f32x4 c) {
#if __has_builtin(__builtin_amdgcn_mfma_f32_16x16x16_bf16)
  return __builtin_amdgcn_mfma_f32_16x16x16_bf16(a, b, c, 0, 0, 0);
#else
  return __builtin_amdgcn_mfma_f32_16x16x16bf16_1k(
      __builtin_bit_cast(s16x4, a), __builtin_bit_cast(s16x4, b), c, 0, 0, 0);
#endif
}

// ---- pos_ids = cumsum(mask)*mask + 1 (B=1, S=4096) ----------------------
__global__ __launch_bounds__(256) void posid_kernel(const int* __restrict__ m,
                                                    int* __restrict__ pids) {
  __shared__ int ps[256];
  int t = threadIdx.x;
  int base = t * 16;
  int loc[16], mv[16];
  int s = 0;
#pragma unroll
  for (int j = 0; j < 16; ++j) { mv[j] = m[base + j]; s += mv[j]; loc[j] = s; }
  ps[t] = s;
  __syncthreads();
  for (int off = 1; off < 256; off <<= 1) {
    int v = (t >= off) ? ps[t - off] : 0;
    __syncthreads();
    ps[t] += v;
    __syncthreads();
  }
  int pre = t ? ps[t - 1] : 0;
#pragma unroll
  for (int j = 0; j < 16; ++j) pids[base + j] = (pre + loc[j]) * mv[j] + 1;
}

// ---- block reduction helper (256 threads) -------------------------------
__device__ inline float blk_sum(float v, float* sred) {
#pragma unroll
  for (int o = 32; o; o >>= 1) v += __shfl_down(v, o, 64);
  int w = threadIdx.x >> 6;
  __syncthreads();
  if ((threadIdx.x & 63) == 0) sred[w] = v;
  __syncthreads();
  return sred[0] + sred[1] + sred[2] + sred[3];
}

// ---- embedding gather + LN (f32 inputs) ----------------------------------
__global__ __launch_bounds__(256) void embed_kernel(
    const int* __restrict__ ids, const int* __restrict__ pids,
    const float* __restrict__ ew, const float* __restrict__ ep,
    const float* __restrict__ et, const float* __restrict__ g,
    const float* __restrict__ b, float* __restrict__ xf,
    bf16_t* __restrict__ xb) {
  __shared__ float sred[4];
  int s = blockIdx.x, t = threadIdx.x;
  long wb = (long)ids[s] * DMODEL;
  long pb = (long)pids[s] * DMODEL;
  float v[3];
#pragma unroll
  for (int j = 0; j < 3; ++j) {
    int d = t + j * 256;
    v[j] = ew[wb + d] + ep[pb + d] + et[d];
  }
  float mu = blk_sum(v[0] + v[1] + v[2], sred) * (1.0f / 768.0f);
  float ss = 0.f;
#pragma unroll
  for (int j = 0; j < 3; ++j) { v[j] -= mu; ss += v[j] * v[j]; }
  float rs = rsqrtf(blk_sum(ss, sred) * (1.0f / 768.0f) + 1e-5f);
#pragma unroll
  for (int j = 0; j < 3; ++j) {
    int d = t + j * 256;
    float o = v[j] * rs * g[d] + b[d];
    xf[(long)s * DMODEL + d] = o;
    xb[(long)s * DMODEL + d] = (bf16_t)o;
  }
}

// ---- LN over f32 tmp -> xf (f32 master) + xb (bf16 mirror) ---------------
__global__ __launch_bounds__(256) void ln_kernel(
    const float* __restrict__ in, const float* __restrict__ g,
    const float* __restrict__ b, float* __restrict__ xf,
    bf16_t* __restrict__ xb) {
  __shared__ float sred[4];
  int row = blockIdx.x, t = threadIdx.x;
  const float* r = in + (long)row * DMODEL;
  float v[3] = {r[t], r[t + 256], r[t + 512]};
  float mu = blk_sum(v[0] + v[1] + v[2], sred) * (1.0f / 768.0f);
  float ss = 0.f;
#pragma unroll
  for (int j = 0; j < 3; ++j) { v[j] -= mu; ss += v[j] * v[j]; }
  float rs = rsqrtf(blk_sum(ss, sred) * (1.0f / 768.0f) + 1e-5f);
#pragma unroll
  for (int j = 0; j < 3; ++j) {
    int d = t + j * 256;
    float o = v[j] * rs * g[d] + b[d];
    xf[(long)row * DMODEL + d] = o;
    xb[(long)row * DMODEL + d] = (bf16_t)o;
  }
}

// ---- f32 -> bf16 transpose (weights), 64x64 tiles ------------------------
__global__ __launch_bounds__(256) void trc_kernel(const float* __restrict__ src,
                                                  bf16_t* __restrict__ dst,
                                                  int R, int C, long srcStride,
                                                  long dstStride) {
  src += (long)blockIdx.z * srcStride;
  dst += (long)blockIdx.z * dstStride;
  __shared__ float tile[64][65];
  int r0 = blockIdx.y * 64, c0 = blockIdx.x * 64;
  int t = threadIdx.x;
  int tr = t >> 4;
  int tc = (t & 15) * 4;
#pragma unroll
  for (int j = 0; j < 4; ++j) {
    int row = tr + j * 16;
    float4 v = *(const float4*)(src + (long)(r0 + row) * C + c0 + tc);
    tile[row][tc] = v.x; tile[row][tc + 1] = v.y;
    tile[row][tc + 2] = v.z; tile[row][tc + 3] = v.w;
  }
  __syncthreads();
#pragma unroll
  for (int j = 0; j < 4; ++j) {
    int row = tr + j * 16;  // dst row within tile (= src col)
    bf16x4 v;
    v[0] = (bf16_t)tile[tc + 0][row]; v[1] = (bf16_t)tile[tc + 1][row];
    v[2] = (bf16_t)tile[tc + 2][row]; v[3] = (bf16_t)tile[tc + 3][row];
    *(bf16x4*)(dst + (long)(c0 + row) * R + r0 + tc) = v;
  }
}

// ---- bf16 -> bf16 transpose (V), 64x64 tiles ------------------------------
__global__ __launch_bounds__(256) void tr_kernel(const bf16_t* __restrict__ src,
                                                 bf16_t* __restrict__ dst,
                                                 int R, int C) {
  __shared__ bf16_t tile[64][68];
  int r0 = blockIdx.y * 64, c0 = blockIdx.x * 64;
  int t = threadIdx.x;
  int tr = t >> 4;
  int tc = (t & 15) * 4;
#pragma unroll
  for (int j = 0; j < 4; ++j) {
    int row = tr + j * 16;
    bf16x4 v = *(const bf16x4*)(src + (long)(r0 + row) * C + c0 + tc);
    tile[row][tc] = v[0]; tile[row][tc + 1] = v[1];
    tile[row][tc + 2] = v[2]; tile[row][tc + 3] = v[3];
  }
  __syncthreads();
#pragma unroll
  for (int j = 0; j < 4; ++j) {
    int row = tr + j * 16;
    bf16x4 v;
    v[0] = tile[tc + 0][row]; v[1] = tile[tc + 1][row];
    v[2] = tile[tc + 2][row]; v[3] = tile[tc + 3][row];
    *(bf16x4*)(dst + (long)(c0 + row) * R + r0 + tc) = v;
  }
}

// ---- main GEMM: C = A(MxK) * Bt(NxK)^T + bias, 128x128 tile, BK=64 -------
// EP 0: out = bf16(acc + bias)          (QKV; z batches over 3 weight sets)
// EP 1: out = bf16(gelu(acc + bias))    (FF1)
// EP 2: tmp = acc + bias + resf         (attn-out proj / FF2, f32 out)
template <int EP>
__global__ __launch_bounds__(256) void gemm_kernel(
    const bf16_t* __restrict__ A, const bf16_t* __restrict__ Bt, long btStride,
    const float* b0, const float* b1, const float* b2,
    bf16_t* __restrict__ out, long outStride, const float* __restrict__ resf,
    float* __restrict__ tmp, int M, int N, int K) {
  int z = blockIdx.z;
  Bt += (long)z * btStride;
  const float* bias = (z == 0) ? b0 : (z == 1 ? b1 : b2);
  out += (long)z * outStride;

  // layout: [k-octet g(0..7)][row(0..127)] x 8 contiguous bf16
  __shared__ __align__(16) bf16_t As[128 * 64];
  __shared__ __align__(16) bf16_t Bs[128 * 64];

  int tid = threadIdx.x;
  int lane = tid & 63;
  int wave = tid >> 6;
  int wm = (wave >> 1) * 64;
  int wn = (wave & 1) * 64;
  int l15 = lane & 15;
  int g4 = lane >> 4;
  int m0 = blockIdx.y * 128;
  int n0 = blockIdx.x * 128;

  f32x4 acc[4][4] = {};

  for (int kt = 0; kt < K; kt += 64) {
    bf16x8 avr[4], bvr[4];
#pragma unroll
    for (int c = 0; c < 4; ++c) {
      int L = c * 256 + tid;
      int gg = L >> 7, row = L & 127;
      avr[c] = *(const bf16x8*)(A + (long)(m0 + row) * K + kt + gg * 8);
      bvr[c] = *(const bf16x8*)(Bt + (long)(n0 + row) * K + kt + gg * 8);
    }
    __syncthreads();  // previous iteration's LDS reads complete
#pragma unroll
    for (int c = 0; c < 4; ++c) {
      int L = c * 256 + tid;
      *(bf16x8*)(As + L * 8) = avr[c];
      *(bf16x8*)(Bs + L * 8) = bvr[c];
    }
    __syncthreads();  // stores visible
#pragma unroll
    for (int ks = 0; ks < 2; ++ks) {
      bf16x8 af[4], bfr[4];
#pragma unroll
      for (int mt = 0; mt < 4; ++mt)
        af[mt] = *(const bf16x8*)(As + (((ks * 4 + g4) * 128) + wm + mt * 16 + l15) * 8);
#pragma unroll
      for (int nt = 0; nt < 4; ++nt)
        bfr[nt] = *(const bf16x8*)(Bs + (((ks * 4 + g4) * 128) + wn + nt * 16 + l15) * 8);
#pragma unroll
      for (int mt = 0; mt < 4; ++mt)
#pragma unroll
        for (int nt = 0; nt < 4; ++nt)
          acc[mt][nt] = __builtin_amdgcn_mfma_f32_16x16x32_bf16(
              af[mt], bfr[nt], acc[mt][nt], 0, 0, 0);
    }
  }

#pragma unroll
  for (int mt = 0; mt < 4; ++mt)
#pragma unroll
    for (int nt = 0; nt < 4; ++nt) {
      int col = n0 + wn + nt * 16 + l15;
      float bval = bias[col];
#pragma unroll
      for (int r = 0; r < 4; ++r) {
        int row = m0 + wm + mt * 16 + g4 * 4 + r;
        float v = acc[mt][nt][r] + bval;
        if (EP == 0) {
          out[(long)row * N + col] = (bf16_t)v;
        } else if (EP == 1) {
          float ge = 0.5f * v * (1.0f + erff(v * 0.70710678118654752f));
          out[(long)row * N + col] = (bf16_t)ge;
        } else {
          tmp[(long)row * N + col] = v + resf[(long)row * N + col];
        }
      }
    }
}

// ---- sliding-window flash attention --------------------------------------
// grid (S/64, H), block 64 (1 wave). q,k: (S,768) bf16; vt: (768,S) bf16.
#define NEGM 30000.0f
__global__ __launch_bounds__(64) void attn_kernel(
    const bf16_t* __restrict__ q, const bf16_t* __restrict__ k,
    const bf16_t* __restrict__ vt, bf16_t* __restrict__ outb) {
  int qt = blockIdx.x * 64;
  int hcol = blockIdx.y * 64;
  int lane = threadIdx.x;
  int l15 = lane & 15, g4 = lane >> 4;
  __shared__ __align__(16) float sbuf[64];

  // Q fragments (B-operand of St = K @ Q^T), scale 1/8 folded in (exact).
  bf16x8 qf[4][2];
#pragma unroll
  for (int nt = 0; nt < 4; ++nt)
#pragma unroll
    for (int ks = 0; ks < 2; ++ks) {
      bf16x8 t = *(const bf16x8*)(q + (long)(qt + nt * 16 + l15) * DMODEL +
                                  hcol + ks * 32 + g4 * 8);
#pragma unroll
      for (int i = 0; i < 8; ++i) t[i] = (bf16_t)((float)t[i] * 0.125f);
      qf[nt][ks] = t;
    }

  f32x4 o[4][4] = {};   // [qmt][dt]; lane r -> O[q=16qmt+4g4+r][d=16dt+l15]
  float mS[4], lS[4];
#pragma unroll
  for (int nt = 0; nt < 4; ++nt) { mS[nt] = -NEGM; lS[nt] = 0.f; }

  int kstart = qt - 256; if (kstart < 0) kstart = 0;
  int kend = qt + 320; if (kend > S_LEN) kend = S_LEN;

  for (int kb = kstart; kb < kend; kb += 64) {
    // St = K_chunk @ Q^T -> St[key=16kt+4g4+r][q=16nt+l15]
    bf16x8 kf[4][2];
#pragma unroll
    for (int kt = 0; kt < 4; ++kt)
#pragma unroll
      for (int ks = 0; ks < 2; ++ks)
        kf[kt][ks] = *(const bf16x8*)(k + (long)(kb + kt * 16 + l15) * DMODEL +
                                      hcol + ks * 32 + g4 * 8);
    f32x4 st[4][4] = {};
#pragma unroll
    for (int kt = 0; kt < 4; ++kt)
#pragma unroll
      for (int nt = 0; nt < 4; ++nt) {
        st[kt][nt] = __builtin_amdgcn_mfma_f32_16x16x32_bf16(
            kf[kt][0], qf[nt][0], st[kt][nt], 0, 0, 0);
        st[kt][nt] = __builtin_amdgcn_mfma_f32_16x16x32_bf16(
            kf[kt][1], qf[nt][1], st[kt][nt], 0, 0, 0);
      }
    // band mask + online softmax stats (per query q = 16nt + l15)
    float alpha[4];
#pragma unroll
    for (int nt = 0; nt < 4; ++nt) {
      int qg = qt + nt * 16 + l15;
      float mx = -NEGM;
#pragma unroll
      for (int kt = 0; kt < 4; ++kt)
#pragma unroll
        for (int r = 0; r < 4; ++r) {
          int kg = kb + kt * 16 + g4 * 4 + r;
          bool valid = (kg >= qg - 256) && (kg <= qg + 256);
          float s = valid ? st[kt][nt][r] : -NEGM;
          st[kt][nt][r] = s;
          mx = fmaxf(mx, s);
        }
      mx = fmaxf(mx, __shfl_xor(mx, 16, 64));
      mx = fmaxf(mx, __shfl_xor(mx, 32, 64));
      float mnew = fmaxf(mS[nt], mx);
      alpha[nt] = exp2f((mS[nt] - mnew) * 1.44269504088896f);
      float ls = 0.f;
#pragma unroll
      for (int kt = 0; kt < 4; ++kt)
#pragma unroll
        for (int r = 0; r < 4; ++r) {
          float p = exp2f((st[kt][nt][r] - mnew) * 1.44269504088896f);
          st[kt][nt][r] = p;
          ls += p;
        }
      ls += __shfl_xor(ls, 16, 64);
      ls += __shfl_xor(ls, 32, 64);
      lS[nt] = lS[nt] * alpha[nt] + ls;
      mS[nt] = mnew;
    }
    // broadcast alpha into O-layout
    if (g4 == 0) {
#pragma unroll
      for (int nt = 0; nt < 4; ++nt) sbuf[nt * 16 + l15] = alpha[nt];
    }
    __syncthreads();
    f32x4 av[4];
#pragma unroll
    for (int qmt = 0; qmt < 4; ++qmt)
      av[qmt] = *(const f32x4*)(sbuf + qmt * 16 + g4 * 4);
#pragma unroll
    for (int qmt = 0; qmt < 4; ++qmt)
#pragma unroll
      for (int dt = 0; dt < 4; ++dt)
#pragma unroll
        for (int r = 0; r < 4; ++r) o[qmt][dt][r] *= av[qmt][r];
    // PV: St lanes are already exactly the A-operand of 16x16x16 MFMA.
#pragma unroll
    for (int kt = 0; kt < 4; ++kt) {
      bf16x4 pa[4];
#pragma unroll
      for (int qmt = 0; qmt < 4; ++qmt)
#pragma unroll
        for (int i = 0; i < 4; ++i) pa[qmt][i] = (bf16_t)st[kt][qmt][i];
      bf16x4 vf[4];
#pragma unroll
      for (int dt = 0; dt < 4; ++dt)
        vf[dt] = *(const bf16x4*)(vt + (long)(hcol + dt * 16 + l15) * S_LEN +
                                  kb + kt * 16 + g4 * 4);
#pragma unroll
      for (int qmt = 0; qmt < 4; ++qmt)
#pragma unroll
        for (int dt = 0; dt < 4; ++dt)
          o[qmt][dt] = mfma16x16x16(pa[qmt], vf[dt], o[qmt][dt]);
    }
    __syncthreads();
  }
  // final normalize by l
  if (g4 == 0) {
#pragma unroll
    for (int nt = 0; nt < 4; ++nt) sbuf[nt * 16 + l15] = lS[nt];
  }
  __syncthreads();
  f32x4 lv[4];
#pragma unroll
  for (int qmt = 0; qmt < 4; ++qmt)
    lv[qmt] = *(const f32x4*)(sbuf + qmt * 16 + g4 * 4);
#pragma unroll
  for (int qmt = 0; qmt < 4; ++qmt)
#pragma unroll
    for (int dt = 0; dt < 4; ++dt)
#pragma unroll
      for (int r = 0; r < 4; ++r)
        outb[(long)(qt + qmt * 16 + g4 * 4 + r) * DMODEL + hcol + dt * 16 +
             l15] = (bf16_t)(o[qmt][dt][r] / lv[qmt][r]);
}

// ---- classifier heads (f32 weights, f32 out) ------------------------------
__global__ __launch_bounds__(256) void cls_kernel(
    const float* __restrict__ xf, const float* cW1, const float* cb1,
    const float* cW2, const float* cb2, const float* dW1,
    const float* db1, const float* dW2, const float* db2,
    float* __restrict__ out) {
  __shared__ float pooled[768];
  __shared__ float hbuf[512];
  int t = threadIdx.x;
  bool dec = (blockIdx.x == 1);
  const float* W1 = dec ? dW1 : cW1;
  const float* B1 = dec ? db1 : cb1;
  const float* W2 = dec ? dW2 : cW2;
  const float* B2 = dec ? db2 : cb2;
  int nout = dec ? 10 : 5;
  float* op = out + (dec ? 5 : 0);
#pragma unroll
  for (int j = 0; j < 3; ++j) pooled[t + j * 256] = xf[t + j * 256];
  __syncthreads();
  for (int n = t; n < 512; n += 256) {
    float a = B1[n];
    for (int k2 = 0; k2 < 768; ++k2)
      a += pooled[k2] * W1[(long)k2 * 512 + n];
    hbuf[n] = fmaxf(a, 0.f);
  }
  __syncthreads();
  if (t < nout) {
    float a = B2[t];
    for (int i = 0; i < 512; ++i) a += hbuf[i] * W2[i * nout + t];
    op[t] = a;
  }
}

// ---- host orchestration --------------------------------------------------
extern "C" void kernel_launch(void* const* d_in, const int* in_sizes, int n_in,
                              void* d_out, int out_size, void* d_ws,
                              size_t ws_size, hipStream_t stream) {
  const int* ids = (const int*)d_in[0];
  const int* amask = (const int*)d_in[1];
  const float* emb_word = (const float*)d_in[2];
  const float* emb_pos = (const float*)d_in[3];
  const float* emb_type = (const float*)d_in[4];
  const float* emb_g = (const float*)d_in[5];
  const float* emb_b = (const float*)d_in[6];
  const float* Wq = (const float*)d_in[7];
  const float* bq = (const float*)d_in[8];
  const float* Wk = (const float*)d_in[9];
  const float* bk = (const float*)d_in[10];
  const float* Wv = (const float*)d_in[11];
  const float* bv = (const float*)d_in[12];
  const float* Wo = (const float*)d_in[13];
  const float* bo = (const float*)d_in[14];
  const float* ln1g = (const float*)d_in[15];
  const float* ln1b = (const float*)d_in[16];
  const float* W1 = (const float*)d_in[17];
  const float* b1 = (const float*)d_in[18];
  const float* W2 = (const float*)d_in[19];
  const float* b2 = (const float*)d_in[20];
  const float* ln2g = (const float*)d_in[21];
  const float* ln2b = (const float*)d_in[22];
  const float* cW1 = (const float*)d_in[23];
  const float* cb1 = (const float*)d_in[24];
  const float* cW2 = (const float*)d_in[25];
  const float* cb2 = (const float*)d_in[26];
  const float* dW1 = (const float*)d_in[27];
  const float* db1 = (const float*)d_in[28];
  const float* dW2 = (const float*)d_in[29];
  const float* db2 = (const float*)d_in[30];
  float* outp = (float*)d_out;

  const size_t SD = (size_t)S_LEN * DMODEL;
  const size_t DD = (size_t)DMODEL * DMODEL;
  const size_t DF = (size_t)DMODEL * FFDIM;
  const size_t SF = (size_t)S_LEN * FFDIM;

  char* p = (char*)d_ws;
  auto carve = [&](size_t bytes) {
    char* r = p;
    p += (bytes + 255) & ~(size_t)255;
    return (void*)r;
  };

  size_t actsBytes = SD * 2 + SD * 4 + 3 * SD * 2 + SD * 2 + SD * 2 + SF * 2 +
                     SD * 4 + S_LEN * 4 + 16 * 256;
  size_t fullW = (36 * DD + 12 * DD + 24 * DF) * 2 + 16 * 256;
  bool full = ws_size >= actsBytes + fullW;

  bf16_t *qkvt, *wot, *w1t, *w2t;
  if (full) {
    qkvt = (bf16_t*)carve(36 * DD * 2);
    wot = (bf16_t*)carve(12 * DD * 2);
    w1t = (bf16_t*)carve(12 * DF * 2);
    w2t = (bf16_t*)carve(12 * DF * 2);
  } else {
    qkvt = (bf16_t*)carve(3 * DD * 2);
    wot = (bf16_t*)carve(DD * 2);
    w1t = (bf16_t*)carve(DF * 2);
    w2t = (bf16_t*)carve(DF * 2);
  }
  bf16_t* xb = (bf16_t*)carve(SD * 2);
  float* xf = (float*)carve(SD * 4);
  bf16_t* qkv = (bf16_t*)carve(3 * SD * 2);
  bf16_t* vt = (bf16_t*)carve(SD * 2);
  bf16_t* attnb = (bf16_t*)carve(SD * 2);
  bf16_t* hbuf = (bf16_t*)carve(SF * 2);
  float* tmp = (float*)carve(SD * 4);
  int* pids = (int*)carve(S_LEN * 4);

  posid_kernel<<<1, 256, 0, stream>>>(amask, pids);
  embed_kernel<<<S_LEN, 256, 0, stream>>>(ids, pids, emb_word, emb_pos,
                                          emb_type, emb_g, emb_b, xf, xb);

  if (full) {
    trc_kernel<<<dim3(12, 12, 12), 256, 0, stream>>>(Wq, qkvt, 768, 768, DD, 3 * DD);
    trc_kernel<<<dim3(12, 12, 12), 256, 0, stream>>>(Wk, qkvt + DD, 768, 768, DD, 3 * DD);
    trc_kernel<<<dim3(12, 12, 12), 256, 0, stream>>>(Wv, qkvt + 2 * DD, 768, 768, DD, 3 * DD);
    trc_kernel<<<dim3(12, 12, 12), 256, 0, stream>>>(Wo, wot, 768, 768, DD, DD);
    trc_kernel<<<dim3(48, 12, 12), 256, 0, stream>>>(W1, w1t, 768, 3072, DF, DF);
    trc_kernel<<<dim3(12, 48, 12), 256, 0, stream>>>(W2, w2t, 3072, 768, DF, DF);
  }

  for (int i = 0; i < NLAYER; ++i) {
    const bf16_t *qkvt_i, *wot_i, *w1t_i, *w2t_i;
    if (full) {
      qkvt_i = qkvt + (size_t)i * 3 * DD;
      wot_i = wot + (size_t)i * DD;
      w1t_i = w1t + (size_t)i * DF;
      w2t_i = w2t + (size_t)i * DF;
    } else {
      trc_kernel<<<dim3(12, 12, 1), 256, 0, stream>>>(Wq + (size_t)i * DD, qkvt, 768, 768, 0, 0);
      trc_kernel<<<dim3(12, 12, 1), 256, 0, stream>>>(Wk + (size_t)i * DD, qkvt + DD, 768, 768, 0, 0);
      trc_kernel<<<dim3(12, 12, 1), 256, 0, stream>>>(Wv + (size_t)i * DD, qkvt + 2 * DD, 768, 768, 0, 0);
      trc_kernel<<<dim3(12, 12, 1), 256, 0, stream>>>(Wo + (size_t)i * DD, wot, 768, 768, 0, 0);
      trc_kernel<<<dim3(48, 12, 1), 256, 0, stream>>>(W1 + (size_t)i * DF, w1t, 768, 3072, 0, 0);
      trc_kernel<<<dim3(12, 48, 1), 256, 0, stream>>>(W2 + (size_t)i * DF, w2t, 3072, 768, 0, 0);
      qkvt_i = qkvt; wot_i = wot; w1t_i = w1t; w2t_i = w2t;
    }
    gemm_kernel<0><<<dim3(6, 32, 3), 256, 0, stream>>>(
        xb, qkvt_i, (long)DD, bq + i * 768, bk + i * 768, bv + i * 768, qkv,
        (long)SD, nullptr, nullptr, S_LEN, 768, 768);
    tr_kernel<<<dim3(12, 64, 1), 256, 0, stream>>>(qkv + 2 * SD, vt, 4096, 768);
    attn_kernel<<<dim3(64, 12), 64, 0, stream>>>(qkv, qkv + SD, vt, attnb);
    gemm_kernel<2><<<dim3(6, 32, 1), 256, 0, stream>>>(
        attnb, wot_i, 0, bo + i * 768, nullptr, nullptr, nullptr, 0, xf, tmp,
        S_LEN, 768, 768);
    ln_kernel<<<S_LEN, 256, 0, stream>>>(tmp, ln1g + i * 768, ln1b + i * 768, xf, xb);
    gemm_kernel<1><<<dim3(24, 32, 1), 256, 0, stream>>>(
        xb, w1t_i, 0, b1 + (size_t)i * FFDIM, nullptr, nullptr, hbuf, 0,
        nullptr, nullptr, S_LEN, FFDIM, 768);
    gemm_kernel<2><<<dim3(6, 32, 1), 256, 0, stream>>>(
        hbuf, w2t_i, 0, b2 + i * 768, nullptr, nullptr, nullptr, 0, xf, tmp,
        S_LEN, 768, FFDIM);
    ln_kernel<<<S_LEN, 256, 0, stream>>>(tmp, ln2g + i * 768, ln2b + i * 768, xf, xb);
  }
  cls_kernel<<<2, 256, 0, stream>>>(xf, cW1, cb1, cW2, cb2, dW1, db1, dW2, db2, outp);
}